// Round 13
// baseline (282.038 us; speedup 1.0000x reference)
//
#include <hip/hip_runtime.h>

// VQ-VAE quantize: input (16,64,64,64) f32, embeddings (64,2048) f32.
// Outputs concat in d_out: quantize_st[4194304], loss[1], embed_ind[65536] (as float).
//
// Correctness-critical (absmax 0.0 rounds 1,2,4-9,12 — arithmetic frozen):
//   dist = fl( fl(sx - 2*dot) + se ),  dot = sequential-k FMA chain (k=0..63),
//   sx = numpy pairwise (8 accumulators + tree; 0-init exact), se = sequential
//   axis-0 sum, argmin = first index of global minimum (strict < per-thread
//   over time-ascending own-codes, then merge on (v<bv)||(v==bv&&idx<bidx)).
//
// Round-13: round-12 was LDS/VALU co-limited (1 B/FMA = exactly the 128 B/cyc
// LDS peak; VALUBusy 66%). Now 16px x 8codes per thread: 128 FMA per 6
// ds_read_b128 = 0.75 B/FMA -> LDS 96 B/cyc < peak, VALU binds. Block =
// 256 px, 128-code chunks; xs[64][256] 64KB + es dbuf 2x32KB = 128KB LDS,
// grid 256 = one exact round at 1 block/CU. All staging via
// global_load_lds (linear lane dest: zero staging VGPRs, zero ds_writes,
// zero write conflicts); direct layout, reads <=2-way (free). One barrier
// per chunk.

#define HW     4096      // 64*64
#define CHW    262144    // 64*4096
#define NE     2048
#define OUT_Q  4194304   // NPIX*DIM
#define WS_SE  0         // se[j]: 2048 floats
#define WS_ACC 2048      // loss accumulator: 1 float
#define INF    3.402823466e38f

__global__ __launch_bounds__(256) void vq_prep(const float* __restrict__ emb,
                                               float* __restrict__ ws) {
  // se[j] = sum_k fl(e_kj^2), sequential over k (numpy axis-0 reduce order)
  int j = blockIdx.x * 256 + threadIdx.x;
  float s = 0.0f;
  for (int k = 0; k < 64; ++k) {
    float e = emb[k * NE + j];
    s = __fadd_rn(s, __fmul_rn(e, e));
  }
  ws[WS_SE + j] = s;
  if (j == 0) ws[WS_ACC] = 0.0f;
}

// async global->LDS, 16B per lane; LDS dest = uniform base + lane*16 (linear)
__device__ __forceinline__ void gll16(const void* g, void* l) {
  __builtin_amdgcn_global_load_lds(
      (const __attribute__((address_space(1))) void*)g,
      (__attribute__((address_space(3))) void*)l, 16, 0, 0);
}

// ---- float4 componentwise helpers (exact rn ops) ----
#define F4ZERO(v) { v.x = 0.f; v.y = 0.f; v.z = 0.f; v.w = 0.f; }
#define F4ADD(d, a, b) { d.x = __fadd_rn(a.x, b.x); d.y = __fadd_rn(a.y, b.y); \
                         d.z = __fadd_rn(a.z, b.z); d.w = __fadd_rn(a.w, b.w); }
#define F4SQACC(r, v) { r.x = __fadd_rn(r.x, __fmul_rn(v.x, v.x)); \
                        r.y = __fadd_rn(r.y, __fmul_rn(v.y, v.y)); \
                        r.z = __fadd_rn(r.z, __fmul_rn(v.z, v.z)); \
                        r.w = __fadd_rn(r.w, __fmul_rn(v.w, v.w)); }
// 8 FMAs into pixel p's two code-quad accumulators (k-ascending chain per acc)
#define FMA8(p, a) { \
  C##p##a_.x = __fmaf_rn(a, bv0.x, C##p##a_.x); C##p##a_.y = __fmaf_rn(a, bv0.y, C##p##a_.y); \
  C##p##a_.z = __fmaf_rn(a, bv0.z, C##p##a_.z); C##p##a_.w = __fmaf_rn(a, bv0.w, C##p##a_.w); \
  C##p##b_.x = __fmaf_rn(a, bv1.x, C##p##b_.x); C##p##b_.y = __fmaf_rn(a, bv1.y, C##p##b_.y); \
  C##p##b_.z = __fmaf_rn(a, bv1.z, C##p##b_.z); C##p##b_.w = __fmaf_rn(a, bv1.w, C##p##b_.w); }
#define DECLC(p) float4 C##p##a_, C##p##b_;
#define ZEROC(p) { F4ZERO(C##p##a_) F4ZERO(C##p##b_) }
// argmin update: pixel slot p, code-quad suffix q (a_/b_), component, code jj+J
#define UPD1(p, q, comp, J) { \
  float dd = __fadd_rn(__fsub_rn(sx_##p, __fmul_rn(2.0f, C##p##q.comp)), sej); \
  if (dd < bb##p) { bb##p = dd; ii##p = jj + (J); } }
#define UPD16(q, comp, J, SE) { const float sej = (SE); \
  UPD1(0,q,comp,J)  UPD1(1,q,comp,J)  UPD1(2,q,comp,J)  UPD1(3,q,comp,J) \
  UPD1(4,q,comp,J)  UPD1(5,q,comp,J)  UPD1(6,q,comp,J)  UPD1(7,q,comp,J) \
  UPD1(8,q,comp,J)  UPD1(9,q,comp,J)  UPD1(10,q,comp,J) UPD1(11,q,comp,J) \
  UPD1(12,q,comp,J) UPD1(13,q,comp,J) UPD1(14,q,comp,J) UPD1(15,q,comp,J) }
// px slot p (0..15) -> pixel index (p>>2)*64 + pg*4 + (p&3)
#define STOR1(p) { const int px_ = ((p)>>2)*64 + pg*4 + ((p)&3); \
  rvv[cg*256 + px_] = bb##p; rii[cg*256 + px_] = ii##p; }
// sx pass: compute sx for the 4 pixels of xs column (i*16+pg) -> sx_{4i..4i+3}
#define SXPASS(i, o0, o1, o2, o3) { \
  float4 r0, r1, r2, r3, r4, r5, r6, r7; \
  F4ZERO(r0) F4ZERO(r1) F4ZERO(r2) F4ZERO(r3) \
  F4ZERO(r4) F4ZERO(r5) F4ZERO(r6) F4ZERO(r7) \
  _Pragma("unroll") \
  for (int blk = 0; blk < 8; ++blk) { \
    float4 v; \
    v = xs4[(blk*8 + 0) * 64 + (i)*16 + pg]; F4SQACC(r0, v) \
    v = xs4[(blk*8 + 1) * 64 + (i)*16 + pg]; F4SQACC(r1, v) \
    v = xs4[(blk*8 + 2) * 64 + (i)*16 + pg]; F4SQACC(r2, v) \
    v = xs4[(blk*8 + 3) * 64 + (i)*16 + pg]; F4SQACC(r3, v) \
    v = xs4[(blk*8 + 4) * 64 + (i)*16 + pg]; F4SQACC(r4, v) \
    v = xs4[(blk*8 + 5) * 64 + (i)*16 + pg]; F4SQACC(r5, v) \
    v = xs4[(blk*8 + 6) * 64 + (i)*16 + pg]; F4SQACC(r6, v) \
    v = xs4[(blk*8 + 7) * 64 + (i)*16 + pg]; F4SQACC(r7, v) \
  } \
  float4 t01, t23, t45, t67, ta, tb, sq; \
  F4ADD(t01, r0, r1) F4ADD(t23, r2, r3) F4ADD(t45, r4, r5) F4ADD(t67, r6, r7) \
  F4ADD(ta, t01, t23) F4ADD(tb, t45, t67) F4ADD(sq, ta, tb) \
  o0 = sq.x; o1 = sq.y; o2 = sq.z; o3 = sq.w; }

__global__ __launch_bounds__(256) void vq_main(const float* __restrict__ inp,
                                               const float* __restrict__ emb,
                                               const float* __restrict__ se,
                                               float* __restrict__ out,
                                               float* __restrict__ loss_acc) {
  __shared__ __align__(16) float xs[64 * 256];      // [k][px] direct, 64 KB
  __shared__ __align__(16) float es[2][64 * 128];   // dbuf [k][code] direct, 64 KB
  float* esf = &es[0][0];
  const float4* xs4 = reinterpret_cast<const float4*>(xs);
  // overlays into es (dead after the main loop):
  float* rvv  = esf;                                   // [16][256]
  int*   rii  = reinterpret_cast<int*>(esf + 4096);    // [16][256]
  int*   bixs = reinterpret_cast<int*>(esf + 8192);    // [256]
  float* lss  = esf + 8448;                            // [4]

  const int tx   = threadIdx.x;
  const int wv   = tx >> 6;                    // wave 0..3 (block-uniform per wave)
  const int b    = blockIdx.x >> 4;            // 16 blocks per batch image
  const int hw0  = (blockIdx.x & 15) << 8;     // 256-pixel contiguous run
  const int pixbase = blockIdx.x << 8;

  // ---- prologue staging, all via global_load_lds (linear lane dest) ----
  // xs[k][*]: 16 rows per wave; lane l -> col 4l..4l+3
  {
    const float* xsrc = inp + (size_t)b * CHW + hw0 + (tx & 63) * 4;
#pragma unroll
    for (int p = 0; p < 16; ++p)
      gll16(xsrc + (p * 4 + wv) * HW, xs + (p * 4 + wv) * 256);
    // es chunk 0: rows p*8 + 2*wv + (l>>5); lane l -> col (l&31)*4
    const float* esrc = emb + (size_t)(tx >> 5) * NE + (tx & 31) * 4;
#pragma unroll
    for (int p = 0; p < 8; ++p)
      gll16(esrc + (p * 8) * NE, &es[0][0] + (p * 8 + 2 * wv) * 128);
  }
  __syncthreads();                             // xs + es[0] landed (vmcnt drained)

  // ---- thread tile: pg -> px cols {pg,16+pg,32+pg,48+pg}; cg -> 8 codes/chunk
  const int pg = tx & 15, cg = tx >> 4;
  const float4* se4 = reinterpret_cast<const float4*>(se);

  // sx: numpy pairwise per pixel (same order as rounds 1-12)
  float sx_0, sx_1, sx_2, sx_3, sx_4, sx_5, sx_6, sx_7;
  float sx_8, sx_9, sx_10, sx_11, sx_12, sx_13, sx_14, sx_15;
  SXPASS(0, sx_0, sx_1, sx_2, sx_3)
  SXPASS(1, sx_4, sx_5, sx_6, sx_7)
  SXPASS(2, sx_8, sx_9, sx_10, sx_11)
  SXPASS(3, sx_12, sx_13, sx_14, sx_15)

  float bb0 = INF, bb1 = INF, bb2 = INF, bb3 = INF;
  float bb4 = INF, bb5 = INF, bb6 = INF, bb7 = INF;
  float bb8 = INF, bb9 = INF, bb10 = INF, bb11 = INF;
  float bb12 = INF, bb13 = INF, bb14 = INF, bb15 = INF;
  int ii0 = 0, ii1 = 0, ii2 = 0, ii3 = 0, ii4 = 0, ii5 = 0, ii6 = 0, ii7 = 0;
  int ii8 = 0, ii9 = 0, ii10 = 0, ii11 = 0, ii12 = 0, ii13 = 0, ii14 = 0, ii15 = 0;

  const float* esrc = emb + (size_t)(tx >> 5) * NE + (tx & 31) * 4;

#pragma unroll 1
  for (int ch = 0; ch < 16; ++ch) {
    // prefetch next chunk into the other buffer (async, zero VGPRs held)
    if (ch < 15) {
      float* dst = &es[(ch + 1) & 1][0] + (2 * wv) * 128;
      const float* src = esrc + (ch + 1) * 128;
#pragma unroll
      for (int p = 0; p < 8; ++p)
        gll16(src + (p * 8) * NE, dst + (p * 8) * 128);
    }
    const float4 sea = se4[ch * 32 + cg * 2];      // se for codes jj..jj+3
    const float4 seb = se4[ch * 32 + cg * 2 + 1];  // jj+4..jj+7

    const float4* er4 = reinterpret_cast<const float4*>(&es[ch & 1][0]);

    DECLC(0)  DECLC(1)  DECLC(2)  DECLC(3)  DECLC(4)  DECLC(5)  DECLC(6)  DECLC(7)
    DECLC(8)  DECLC(9)  DECLC(10) DECLC(11) DECLC(12) DECLC(13) DECLC(14) DECLC(15)
    ZEROC(0)  ZEROC(1)  ZEROC(2)  ZEROC(3)  ZEROC(4)  ZEROC(5)  ZEROC(6)  ZEROC(7)
    ZEROC(8)  ZEROC(9)  ZEROC(10) ZEROC(11) ZEROC(12) ZEROC(13) ZEROC(14) ZEROC(15)

#pragma unroll 2
    for (int k = 0; k < 64; ++k) {
      const float4 av0 = xs4[k * 64 + pg];         // px 4pg..4pg+3
      const float4 av1 = xs4[k * 64 + 16 + pg];    // px 64+4pg..
      const float4 av2 = xs4[k * 64 + 32 + pg];    // px 128+4pg..
      const float4 av3 = xs4[k * 64 + 48 + pg];    // px 192+4pg..
      const float4 bv0 = er4[k * 32 + cg * 2];     // codes 8cg..8cg+3
      const float4 bv1 = er4[k * 32 + cg * 2 + 1]; // codes 8cg+4..8cg+7
      FMA8(0,  av0.x) FMA8(1,  av0.y) FMA8(2,  av0.z) FMA8(3,  av0.w)
      FMA8(4,  av1.x) FMA8(5,  av1.y) FMA8(6,  av1.z) FMA8(7,  av1.w)
      FMA8(8,  av2.x) FMA8(9,  av2.y) FMA8(10, av2.z) FMA8(11, av2.w)
      FMA8(12, av3.x) FMA8(13, av3.y) FMA8(14, av3.z) FMA8(15, av3.w)
    }

    // dist + per-thread argmin (codes ascend: quad a comps then quad b comps)
    const int jj = ch * 128 + cg * 8;
    UPD16(a_, x, 0, sea.x) UPD16(a_, y, 1, sea.y) UPD16(a_, z, 2, sea.z) UPD16(a_, w, 3, sea.w)
    UPD16(b_, x, 4, seb.x) UPD16(b_, y, 5, seb.y) UPD16(b_, z, 6, seb.z) UPD16(b_, w, 7, seb.w)

    __syncthreads();   // readers of es[ch&1] done; prefetch into es[(ch+1)&1] landed
  }

  // ---- merge across 16 code-groups (overlay in dead es; idx tie-break = lowest j)
  STOR1(0)  STOR1(1)  STOR1(2)  STOR1(3)  STOR1(4)  STOR1(5)  STOR1(6)  STOR1(7)
  STOR1(8)  STOR1(9)  STOR1(10) STOR1(11) STOR1(12) STOR1(13) STOR1(14) STOR1(15)
  __syncthreads();
  {
    float bv = rvv[tx];
    int   bx = rii[tx];
#pragma unroll
    for (int g = 1; g < 16; ++g) {
      float v  = rvv[g * 256 + tx];
      int   ix = rii[g * 256 + tx];
      if (v < bv || (v == bv && ix < bx)) { bv = v; bx = ix; }
    }
    bixs[tx] = bx;
    out[OUT_Q + 1 + pixbase + tx] = (float)bx;
  }
  __syncthreads();

  // ---- epilogue: thread handles pixel tx, all 64 channels
  {
    const int bx = bixs[tx];
    float* op = out + (size_t)b * CHW + hw0 + tx;
    float lsum = 0.0f;
#pragma unroll 8
    for (int c = 0; c < 64; ++c) {
      float xv = xs[c * 256 + tx];                 // LDS, 2-way max
      float qv = emb[(size_t)c * NE + bx];         // gather, L2-hot
      float d  = __fsub_rn(qv, xv);
      op[c * HW] = __fadd_rn(xv, d);               // x + (q - x)
      lsum = __fadd_rn(lsum, __fmul_rn(d, d));
    }
#pragma unroll
    for (int off = 32; off > 0; off >>= 1)
      lsum = __fadd_rn(lsum, __shfl_xor(lsum, off, 64));
    if ((tx & 63) == 0) lss[wv] = lsum;
  }
  __syncthreads();
  if (tx == 0) {
    float s = __fadd_rn(__fadd_rn(lss[0], lss[1]), __fadd_rn(lss[2], lss[3]));
    atomicAdd(loss_acc, s);
  }
}

__global__ void vq_final(const float* __restrict__ ws, float* __restrict__ out) {
  float m = ws[WS_ACC] / 4194304.0f;              // exact pow2 divide
  out[OUT_Q] = __fadd_rn(m, __fmul_rn(0.25f, m)); // mean + 0.25*mean
}

extern "C" void kernel_launch(void* const* d_in, const int* in_sizes, int n_in,
                              void* d_out, int out_size, void* d_ws, size_t ws_size,
                              hipStream_t stream) {
  const float* inp = (const float*)d_in[0];
  const float* emb = (const float*)d_in[1];
  float* out = (float*)d_out;
  float* ws  = (float*)d_ws;

  vq_prep<<<8, 256, 0, stream>>>(emb, ws);
  vq_main<<<256, 256, 0, stream>>>(inp, emb, ws + WS_SE, out, ws + WS_ACC);
  vq_final<<<1, 1, 0, stream>>>(ws, out);
}